// Round 8
// baseline (1422.331 us; speedup 1.0000x reference)
//
#include <hip/hip_runtime.h>
#include <math.h>

// Problem constants
#define SEQ 4096
#define LL  4097           // sequence + CLS
#define HDIM 32
#define NHEAD 8
#define HD 4
#define FFD 2048
#define NLAYER 6
#define EPSLN 1e-5f
#define NCHUNK 16          // split-K chunks over keys 1..4096 (256 keys each)
#define QB 2               // queries per thread in k_attn

#if __has_builtin(__builtin_amdgcn_exp2f)
#define EXP2 __builtin_amdgcn_exp2f
#else
#define EXP2 exp2f
#endif

#define QSCALE 0.7213475204444817f   // 0.5 * log2(e): folds 1/sqrt(HD) and exp->exp2

typedef float v2f __attribute__((ext_vector_type(2)));
#define FMA2(a, b, c) __builtin_elementwise_fma((a), (b), (c))

__device__ __forceinline__ float dot4(float4 a, float4 b) {
  return fmaf(a.w, b.w, fmaf(a.z, b.z, fmaf(a.y, b.y, a.x * b.x)));
}

// partial sums (implicit m=0), coalesced layout:
//   LP[(c*8+h)*LL + q]  : float   denominator partial
//   AP[(c*8+h)*LL + q]  : float4  numerator partial

// -------- embed (relu(lin)+PE, CLS=-1) fused with layer-0 qkv ---------------
__global__ __launch_bounds__(256) void k_embed_qkv(const float* __restrict__ data,
    const float* __restrict__ lin_w, const float* __restrict__ lin_b,
    float* __restrict__ x, const float* __restrict__ qw,
    const float* __restrict__ qb, float* __restrict__ qkv) {
  __shared__ float xs[8][33];
  int tid = threadIdx.x;
  int r = tid >> 5, ch = tid & 31;
  int row = blockIdx.x * 8 + r;
  bool ok = row < LL;
  float val = 0.f;
  if (ok) {
    if (row == 0) {
      val = -1.0f;
    } else {
      int s = row - 1;
      float ts = data[s * 3 + 0];
      float f0 = data[s * 3 + 1];
      float f1 = data[s * 3 + 2];
      float lin = f0 * lin_w[ch * 2 + 0] + f1 * lin_w[ch * 2 + 1] + lin_b[ch];
      lin = fmaxf(lin, 0.0f);
      int tsi = (int)(ts / 100.0f);
      int j = ch >> 1;
      float aj = (float)(2 * j) * (float)(-0.28782313662425575);
      float divj = (float)exp((double)aj);
      float ang = (float)tsi * divj;
      float pe = (ch & 1) ? cosf(ang) : sinf(ang);
      val = lin + pe;
    }
    x[(size_t)row * HDIM + ch] = val;
  }
  xs[r][ch] = val;
  __syncthreads();
  if (!ok) return;
#pragma unroll
  for (int t3 = 0; t3 < 3; ++t3) {
    int cc = t3 * 32 + ch;
    const float4* wr = (const float4*)(qw + (size_t)cc * HDIM);
    float acc = qb[cc];
#pragma unroll
    for (int k = 0; k < 8; ++k) {
      float4 wv = wr[k];
      acc = fmaf(xs[r][4 * k + 0], wv.x, acc);
      acc = fmaf(xs[r][4 * k + 1], wv.y, acc);
      acc = fmaf(xs[r][4 * k + 2], wv.z, acc);
      acc = fmaf(xs[r][4 * k + 3], wv.w, acc);
    }
    qkv[(size_t)row * 96 + cc] = acc;
  }
}

// ---- attention partials: flat exp2, split-K, packed-fp32 key pairs ---------
// grid (9, NHEAD, NCHUNK). bx<8: q = bx*512 + i*256 + tid covers 0..4095.
// bx==8: q=4096 via key-parallel reduction.
// chunk c covers keys 1+c*256 .. 256+c*256 (key 0 handled in k_layer).
__global__ __launch_bounds__(256, 6) void k_attn(const float* __restrict__ qkv,
    float* __restrict__ LP, float4* __restrict__ AP) {
  int tid = threadIdx.x;
  int h = blockIdx.y;
  int c = blockIdx.z;
  int kbase = 1 + c * 256;
  size_t base = ((size_t)c * NHEAD + h) * LL;

  if (blockIdx.x == 8) {
    __shared__ float rl[256];
    __shared__ float4 ra[256];
    float4 q = *(const float4*)(qkv + (size_t)4096 * 96 + h * HD);
    q.x *= QSCALE; q.y *= QSCALE; q.z *= QSCALE; q.w *= QSCALE;
    float4 kv = *(const float4*)(qkv + (size_t)(kbase + tid) * 96 + 32 + h * HD);
    float4 vv = *(const float4*)(qkv + (size_t)(kbase + tid) * 96 + 64 + h * HD);
    float p = EXP2(dot4(q, kv));
    rl[tid] = p;
    ra[tid] = make_float4(p * vv.x, p * vv.y, p * vv.z, p * vv.w);
    __syncthreads();
    for (int s = 128; s > 0; s >>= 1) {
      if (tid < s) {
        rl[tid] += rl[tid + s];
        ra[tid].x += ra[tid + s].x;
        ra[tid].y += ra[tid + s].y;
        ra[tid].z += ra[tid + s].z;
        ra[tid].w += ra[tid + s].w;
      }
      __syncthreads();
    }
    if (tid == 0) {
      LP[base + 4096] = rl[0];
      AP[base + 4096] = ra[0];
    }
    return;
  }

  __shared__ float ktp[128 * 8];   // 128 key-pairs x {d0..d3}x{lo,hi}
  __shared__ float4 vt[256];
  {
    float4 kv = *(const float4*)(qkv + (size_t)(kbase + tid) * 96 + 32 + h * HD);
    float* bp = ktp + (tid >> 1) * 8 + (tid & 1);
    bp[0] = kv.x; bp[2] = kv.y; bp[4] = kv.z; bp[6] = kv.w;
    vt[tid] = *(const float4*)(qkv + (size_t)(kbase + tid) * 96 + 64 + h * HD);
  }

  v2f qb2[QB][4];
  v2f l2[QB], a01[QB], a23[QB];
  int q0 = blockIdx.x * 512 + tid;
#pragma unroll
  for (int i = 0; i < QB; ++i) {
    int q = q0 + i * 256;
    float4 t = *(const float4*)(qkv + (size_t)q * 96 + h * HD);
    t.x *= QSCALE; t.y *= QSCALE; t.z *= QSCALE; t.w *= QSCALE;
    qb2[i][0] = (v2f){t.x, t.x};
    qb2[i][1] = (v2f){t.y, t.y};
    qb2[i][2] = (v2f){t.z, t.z};
    qb2[i][3] = (v2f){t.w, t.w};
    l2[i] = (v2f){0.f, 0.f};
    a01[i] = (v2f){0.f, 0.f};
    a23[i] = (v2f){0.f, 0.f};
  }
  __syncthreads();

  const v2f* vv2 = (const v2f*)vt;
#pragma unroll 2
  for (int p = 0; p < 128; ++p) {
    const v2f* kp = (const v2f*)(ktp + p * 8);
    v2f kp0 = kp[0], kp1 = kp[1], kp2 = kp[2], kp3 = kp[3];
    v2f va01 = vv2[4 * p + 0], va23 = vv2[4 * p + 1];
    v2f vb01 = vv2[4 * p + 2], vb23 = vv2[4 * p + 3];
#pragma unroll
    for (int i = 0; i < QB; ++i) {
      v2f s2 = qb2[i][0] * kp0;
      s2 = FMA2(qb2[i][1], kp1, s2);
      s2 = FMA2(qb2[i][2], kp2, s2);
      s2 = FMA2(qb2[i][3], kp3, s2);
      v2f pv;
      pv.x = EXP2(s2.x);
      pv.y = EXP2(s2.y);
      l2[i] += pv;
      v2f pa = pv.xx;
      v2f pb = pv.yy;
      a01[i] = FMA2(pa, va01, a01[i]);
      a23[i] = FMA2(pa, va23, a23[i]);
      a01[i] = FMA2(pb, vb01, a01[i]);
      a23[i] = FMA2(pb, vb23, a23[i]);
    }
  }

#pragma unroll
  for (int i = 0; i < QB; ++i) {
    size_t idx = base + q0 + i * 256;
    LP[idx] = l2[i].x + l2[i].y;
    AP[idx] = make_float4(a01[i].x, a01[i].y, a23[i].x, a23[i].y);
  }
}

// ---- mega-fused per-layer tail: combine partials + o-proj + LN1 + full FFN
//      + LN2 + next-layer qkv. 513 blocks x 8-row tiles, 256 threads.
// Streams W1/W2 through LDS in 16 chunks of 128 ff-cols; output partial kept
// in a float4 register across chunks. qkv double-buffered (qkv_in read in
// phase A incl. row 0's k/v -> must not be overwritten -> write qkv_out).
__global__ __launch_bounds__(256) void k_layer(const float* __restrict__ LP,
    const float4* __restrict__ AP, const float* __restrict__ qkv_in,
    float* __restrict__ x,
    const float* __restrict__ ow, const float* __restrict__ ob,
    const float* __restrict__ ln1g, const float* __restrict__ ln1b,
    const float* __restrict__ w1, const float* __restrict__ fb1,
    const float* __restrict__ w2, const float* __restrict__ fb2,
    const float* __restrict__ ln2g, const float* __restrict__ ln2b,
    const float* __restrict__ qw, const float* __restrict__ qb,
    float* __restrict__ qkv_out, int do_qkv) {
  __shared__ float os[8][33];
  __shared__ float Xs[8][36];      // rows 144 B (16B-aligned for b128 reads)
  __shared__ float W1c[128][36];   // W1 chunk, col-major rows
  __shared__ float W2s[32][132];   // W2 chunk, out-col-major rows
  __shared__ float Fs[8][132];     // f tile
  int tid = threadIdx.x;
  int r = tid >> 5, ch = tid & 31;
  int row = blockIdx.x * 8 + r;
  bool ok = row < LL;

  // ---- phase A: combine split-K partials + analytic key-0 + o-proj + LN1 ---
  if (ok) {
    int h = ch >> 2, d = ch & 3;
    float L = 0.f, A = 0.f;
#pragma unroll
    for (int c = 0; c < NCHUNK; ++c) {
      size_t idx = ((size_t)c * NHEAD + h) * LL + row;
      L += LP[idx];
      A += ((const float*)&AP[idx])[d];
    }
    float4 q4 = *(const float4*)(qkv_in + (size_t)row * 96 + h * HD);
    float4 k04 = *(const float4*)(qkv_in + 32 + h * HD);
    float p0 = EXP2(QSCALE * dot4(q4, k04));
    L += p0;
    A = fmaf(p0, qkv_in[64 + h * HD + d], A);
    os[r][ch] = A / L;
  } else {
    os[r][ch] = 0.f;
  }
  __syncthreads();
  float acc0 = 0.f;
#pragma unroll
  for (int k = 0; k < 32; ++k) acc0 = fmaf(os[r][k], ow[ch * 32 + k], acc0);
  float val = ok ? (x[(size_t)row * HDIM + ch] + acc0 + ob[ch]) : 0.f;
  float mean = val;
#pragma unroll
  for (int off = 16; off > 0; off >>= 1) mean += __shfl_xor(mean, off, 32);
  mean *= (1.f / 32.f);
  float dd = val - mean;
  float var = dd * dd;
#pragma unroll
  for (int off = 16; off > 0; off >>= 1) var += __shfl_xor(var, off, 32);
  var *= (1.f / 32.f);
  float y1 = dd / sqrtf(var + EPSLN) * ln1g[ch] + ln1b[ch];
  Xs[r][ch] = ok ? y1 : 0.f;    // post-LN1 row kept on-chip only

  // ---- phase B: FFN over 16 chunks of 128 ff-cols ----
  float4 s4 = make_float4(0.f, 0.f, 0.f, 0.f);
  int g1 = tid >> 7, c1 = tid & 127;
  for (int cc = 0; cc < 16; ++cc) {
    int f0 = cc * 128;
    __syncthreads();   // Xs ready (first iter) / prev phase-2 done (others)
#pragma unroll
    for (int p = 0; p < 16; ++p) {
      int idx = p * 256 + tid;
      int c = idx >> 5, k = idx & 31;
      W1c[c][k] = w1[(size_t)(f0 + c) * HDIM + k];
    }
#pragma unroll
    for (int p = 0; p < 16; ++p) {
      int idx = p * 256 + tid;
      int c = idx >> 7, k = idx & 127;
      W2s[c][k] = w2[(size_t)c * FFD + f0 + k];
    }
    __syncthreads();
    // phase 1: f[g1*4+i][c1] = relu(X-row . W1col)
    float bb = fb1[f0 + c1];
    float fv0 = bb, fv1 = bb, fv2 = bb, fv3 = bb;
#pragma unroll
    for (int j = 0; j < 8; ++j) {
      float4 w4 = *(const float4*)&W1c[c1][4 * j];
      float4 x0 = *(const float4*)&Xs[g1 * 4 + 0][4 * j];
      float4 x1 = *(const float4*)&Xs[g1 * 4 + 1][4 * j];
      float4 x2 = *(const float4*)&Xs[g1 * 4 + 2][4 * j];
      float4 x3 = *(const float4*)&Xs[g1 * 4 + 3][4 * j];
      fv0 = fmaf(x0.x, w4.x, fv0); fv0 = fmaf(x0.y, w4.y, fv0);
      fv0 = fmaf(x0.z, w4.z, fv0); fv0 = fmaf(x0.w, w4.w, fv0);
      fv1 = fmaf(x1.x, w4.x, fv1); fv1 = fmaf(x1.y, w4.y, fv1);
      fv1 = fmaf(x1.z, w4.z, fv1); fv1 = fmaf(x1.w, w4.w, fv1);
      fv2 = fmaf(x2.x, w4.x, fv2); fv2 = fmaf(x2.y, w4.y, fv2);
      fv2 = fmaf(x2.z, w4.z, fv2); fv2 = fmaf(x2.w, w4.w, fv2);
      fv3 = fmaf(x3.x, w4.x, fv3); fv3 = fmaf(x3.y, w4.y, fv3);
      fv3 = fmaf(x3.z, w4.z, fv3); fv3 = fmaf(x3.w, w4.w, fv3);
    }
    Fs[g1 * 4 + 0][c1] = fmaxf(fv0, 0.f);
    Fs[g1 * 4 + 1][c1] = fmaxf(fv1, 0.f);
    Fs[g1 * 4 + 2][c1] = fmaxf(fv2, 0.f);
    Fs[g1 * 4 + 3][c1] = fmaxf(fv3, 0.f);
    __syncthreads();
    // phase 2: s4 += f[r][:] . W2col[ch][:]
#pragma unroll 8
    for (int j = 0; j < 32; ++j) {
      float4 fv = *(const float4*)&Fs[r][4 * j];
      float4 w4 = *(const float4*)&W2s[ch][4 * j];
      s4.x = fmaf(fv.x, w4.x, s4.x);
      s4.y = fmaf(fv.y, w4.y, s4.y);
      s4.z = fmaf(fv.z, w4.z, s4.z);
      s4.w = fmaf(fv.w, w4.w, s4.w);
    }
  }
  float ffn = (s4.x + s4.y) + (s4.z + s4.w);

  // ---- phase C: residual + LN2, write x ----
  float val2 = ok ? (Xs[r][ch] + ffn + fb2[ch]) : 0.f;
  float mean2 = val2;
#pragma unroll
  for (int off = 16; off > 0; off >>= 1) mean2 += __shfl_xor(mean2, off, 32);
  mean2 *= (1.f / 32.f);
  float d2 = val2 - mean2;
  float var2 = d2 * d2;
#pragma unroll
  for (int off = 16; off > 0; off >>= 1) var2 += __shfl_xor(var2, off, 32);
  var2 *= (1.f / 32.f);
  float y2 = d2 / sqrtf(var2 + EPSLN) * ln2g[ch] + ln2b[ch];
  if (ok) x[(size_t)row * HDIM + ch] = y2;
  Xs[r][ch] = ok ? y2 : 0.f;
  __syncthreads();

  // ---- phase D: next-layer qkv ----
  if (!do_qkv || !ok) return;
#pragma unroll
  for (int t3 = 0; t3 < 3; ++t3) {
    int cq = t3 * 32 + ch;
    const float4* wr = (const float4*)(qw + (size_t)cq * HDIM);
    float acc = qb[cq];
#pragma unroll
    for (int k = 0; k < 8; ++k) {
      float4 wv = wr[k];
      acc = fmaf(Xs[r][4 * k + 0], wv.x, acc);
      acc = fmaf(Xs[r][4 * k + 1], wv.y, acc);
      acc = fmaf(Xs[r][4 * k + 2], wv.z, acc);
      acc = fmaf(Xs[r][4 * k + 3], wv.w, acc);
    }
    qkv_out[(size_t)row * 96 + cq] = acc;
  }
}

// ---------------- final: sigmoid(x[0] . cls_w + cls_b) -----------------------
__global__ void k_final(const float* __restrict__ x, const float* __restrict__ cw,
                        const float* __restrict__ cb, float* __restrict__ out) {
  int t = threadIdx.x;   // 64 threads
  float v = (t < 32) ? x[t] * cw[t] : 0.f;
#pragma unroll
  for (int off = 32; off > 0; off >>= 1) v += __shfl_xor(v, off, 64);
  if (t == 0) {
    float z = v + cb[0];
    out[0] = 1.f / (1.f + expf(-z));
  }
}

extern "C" void kernel_launch(void* const* d_in, const int* in_sizes, int n_in,
                              void* d_out, int out_size, void* d_ws, size_t ws_size,
                              hipStream_t stream) {
  const float* data  = (const float*)d_in[0];
  const float* lin_w = (const float*)d_in[1];
  const float* lin_b = (const float*)d_in[2];
  const float* qkv_w = (const float*)d_in[3];
  const float* qkv_b = (const float*)d_in[4];
  const float* out_w = (const float*)d_in[5];
  const float* out_b = (const float*)d_in[6];
  const float* ln1_g = (const float*)d_in[7];
  const float* ln1_b = (const float*)d_in[8];
  const float* ff1_w = (const float*)d_in[9];
  const float* ff1_b = (const float*)d_in[10];
  const float* ff2_w = (const float*)d_in[11];
  const float* ff2_b = (const float*)d_in[12];
  const float* ln2_g = (const float*)d_in[13];
  const float* ln2_b = (const float*)d_in[14];
  const float* cls_w = (const float*)d_in[15];
  const float* cls_b = (const float*)d_in[16];

  float* ws = (float*)d_ws;
  float*  X    = ws;                            // LL*32
  float*  QKVa = X + (size_t)LL * 32;           // LL*96
  float*  QKVb = QKVa + (size_t)LL * 96;        // LL*96
  float4* AP   = (float4*)(QKVb + (size_t)LL * 96);          // NCHUNK*NHEAD*LL
  float*  LP   = (float*)(AP + (size_t)NCHUNK * NHEAD * LL); // NCHUNK*NHEAD*LL

  const int NROWB = (LL + 7) / 8;               // 513

  k_embed_qkv<<<NROWB, 256, 0, stream>>>(data, lin_w, lin_b, X,
                                         qkv_w, qkv_b, QKVa);
  for (int l = 0; l < NLAYER; ++l) {
    float* qkv_cur = (l & 1) ? QKVb : QKVa;
    float* qkv_nxt = (l & 1) ? QKVa : QKVb;
    k_attn<<<dim3(9, NHEAD, NCHUNK), 256, 0, stream>>>(qkv_cur, LP, AP);
    int nl = l + 1;
    int do_qkv = (nl < NLAYER) ? 1 : 0;
    const float* qw = qkv_w + (size_t)(do_qkv ? nl : 0) * 96 * 32;
    const float* qb = qkv_b + (size_t)(do_qkv ? nl : 0) * 96;
    k_layer<<<NROWB, 256, 0, stream>>>(
        LP, AP, qkv_cur, X,
        out_w + (size_t)l * 32 * 32, out_b + (size_t)l * 32,
        ln1_g + (size_t)l * 32, ln1_b + (size_t)l * 32,
        ff1_w + (size_t)l * FFD * 32, ff1_b + (size_t)l * FFD,
        ff2_w + (size_t)l * 32 * FFD, ff2_b + (size_t)l * 32,
        ln2_g + (size_t)l * 32, ln2_b + (size_t)l * 32,
        qw, qb, qkv_nxt, do_qkv);
  }
  k_final<<<1, 64, 0, stream>>>(X, cls_w, cls_b, (float*)d_out);
}

// Round 9
// 646.473 us; speedup vs baseline: 2.2001x; 2.2001x over previous
//
#include <hip/hip_runtime.h>
#include <math.h>

// Problem constants
#define SEQ 4096
#define LL  4097           // sequence + CLS
#define HDIM 32
#define NHEAD 8
#define HD 4
#define FFD 2048
#define NLAYER 6
#define EPSLN 1e-5f
#define NCHUNK 16          // split-K chunks over keys 1..4096 (256 keys each)
#define QB 2               // queries per thread in k_attn
#define RT 64              // FFN row tile
#define FS 128             // FFN f-segment width
#define NFS 16             // FFD / FS

#if __has_builtin(__builtin_amdgcn_exp2f)
#define EXP2 __builtin_amdgcn_exp2f
#else
#define EXP2 exp2f
#endif

#define QSCALE 0.7213475204444817f   // 0.5 * log2(e): folds 1/sqrt(HD) and exp->exp2

typedef float v2f __attribute__((ext_vector_type(2)));
#define FMA2(a, b, c) __builtin_elementwise_fma((a), (b), (c))

__device__ __forceinline__ float dot4(float4 a, float4 b) {
  return fmaf(a.w, b.w, fmaf(a.z, b.z, fmaf(a.y, b.y, a.x * b.x)));
}

// partial sums (implicit m=0), coalesced layout:
//   LP[(c*8+h)*LL + q]  : float   denominator partial
//   AP[(c*8+h)*LL + q]  : float4  numerator partial
// K pair-transposed:  KT[((h*2048+p)*8) + d*2 + par]  (keys 1..4096, p=(k-1)>>1)
// V head-contiguous:  VT[((h*4097+k)*4) + d]

__device__ __forceinline__ void store_ktvt(int row, int ch, int t3, float acc,
    float* __restrict__ KT, float* __restrict__ VT) {
  int h = ch >> 2, d = ch & 3;
  if (t3 == 1) {           // K part
    if (row >= 1) {
      int p = (row - 1) >> 1, par = (row - 1) & 1;
      KT[(((size_t)h * 2048 + p) << 3) + d * 2 + par] = acc;
    }
  } else if (t3 == 2) {    // V part
    if (row >= 1) {
      VT[(((size_t)h * 4097 + row) << 2) + d] = acc;
    }
  }
}

// -------- embed (relu(lin)+PE, CLS=-1) fused with layer-0 qkv ---------------
__global__ __launch_bounds__(256) void k_embed_qkv(const float* __restrict__ data,
    const float* __restrict__ lin_w, const float* __restrict__ lin_b,
    float* __restrict__ x, const float* __restrict__ qw,
    const float* __restrict__ qb, float* __restrict__ qkv,
    float* __restrict__ KT, float* __restrict__ VT) {
  __shared__ float xs[8][33];
  int tid = threadIdx.x;
  int r = tid >> 5, ch = tid & 31;
  int row = blockIdx.x * 8 + r;
  bool ok = row < LL;
  float val = 0.f;
  if (ok) {
    if (row == 0) {
      val = -1.0f;
    } else {
      int s = row - 1;
      float ts = data[s * 3 + 0];
      float f0 = data[s * 3 + 1];
      float f1 = data[s * 3 + 2];
      float lin = f0 * lin_w[ch * 2 + 0] + f1 * lin_w[ch * 2 + 1] + lin_b[ch];
      lin = fmaxf(lin, 0.0f);
      int tsi = (int)(ts / 100.0f);
      int j = ch >> 1;
      float aj = (float)(2 * j) * (float)(-0.28782313662425575);
      float divj = (float)exp((double)aj);
      float ang = (float)tsi * divj;
      float pe = (ch & 1) ? cosf(ang) : sinf(ang);
      val = lin + pe;
    }
    x[(size_t)row * HDIM + ch] = val;
  }
  xs[r][ch] = val;
  __syncthreads();
  if (!ok) return;
#pragma unroll
  for (int t3 = 0; t3 < 3; ++t3) {
    int cc = t3 * 32 + ch;
    const float4* wr = (const float4*)(qw + (size_t)cc * HDIM);
    float acc = qb[cc];
#pragma unroll
    for (int k = 0; k < 8; ++k) {
      float4 wv = wr[k];
      acc = fmaf(xs[r][4 * k + 0], wv.x, acc);
      acc = fmaf(xs[r][4 * k + 1], wv.y, acc);
      acc = fmaf(xs[r][4 * k + 2], wv.z, acc);
      acc = fmaf(xs[r][4 * k + 3], wv.w, acc);
    }
    qkv[(size_t)row * 96 + cc] = acc;
    store_ktvt(row, ch, t3, acc, KT, VT);
  }
}

// ---- attention partials: flat exp2, split-K, LDS-free main loop ------------
// grid (9, NHEAD, NCHUNK). bx<8: q = bx*512 + i*256 + tid covers 0..4095.
// bx==8: q=4096 via key-parallel reduction (reads plain qkv).
// chunk c covers keys 1+c*256 .. 256+c*256 (key 0 handled in k_oproj).
// K/V pairs read straight from KT/VT (L1-resident 8 KB slice per block).
__global__ __launch_bounds__(256) void k_attn(const float* __restrict__ qkv,
    const float* __restrict__ KT, const float* __restrict__ VT,
    float* __restrict__ LP, float4* __restrict__ AP) {
  int tid = threadIdx.x;
  int h = blockIdx.y;
  int c = blockIdx.z;
  int kbase = 1 + c * 256;
  size_t base = ((size_t)c * NHEAD + h) * LL;

  if (blockIdx.x == 8) {
    __shared__ float rl[256];
    __shared__ float4 ra[256];
    float4 q = *(const float4*)(qkv + (size_t)4096 * 96 + h * HD);
    q.x *= QSCALE; q.y *= QSCALE; q.z *= QSCALE; q.w *= QSCALE;
    float4 kv = *(const float4*)(qkv + (size_t)(kbase + tid) * 96 + 32 + h * HD);
    float4 vv = *(const float4*)(qkv + (size_t)(kbase + tid) * 96 + 64 + h * HD);
    float p = EXP2(dot4(q, kv));
    rl[tid] = p;
    ra[tid] = make_float4(p * vv.x, p * vv.y, p * vv.z, p * vv.w);
    __syncthreads();
    for (int s = 128; s > 0; s >>= 1) {
      if (tid < s) {
        rl[tid] += rl[tid + s];
        ra[tid].x += ra[tid + s].x;
        ra[tid].y += ra[tid + s].y;
        ra[tid].z += ra[tid + s].z;
        ra[tid].w += ra[tid + s].w;
      }
      __syncthreads();
    }
    if (tid == 0) {
      LP[base + 4096] = rl[0];
      AP[base + 4096] = ra[0];
    }
    return;
  }

  // main path: 512 queries per block, 128 key-pairs, no LDS / no barriers
  const v2f* KTh = (const v2f*)(KT + (((size_t)h * 2048 + c * 128) << 3));
  const v2f* VTh = (const v2f*)(VT + (((size_t)h * 4097 + kbase) << 2));

  v2f qb2[QB][4];
  v2f l2[QB], a01[QB], a23[QB];
  int q0 = blockIdx.x * 512 + tid;
#pragma unroll
  for (int i = 0; i < QB; ++i) {
    int q = q0 + i * 256;
    float4 t = *(const float4*)(qkv + (size_t)q * 96 + h * HD);
    t.x *= QSCALE; t.y *= QSCALE; t.z *= QSCALE; t.w *= QSCALE;
    qb2[i][0] = (v2f){t.x, t.x};
    qb2[i][1] = (v2f){t.y, t.y};
    qb2[i][2] = (v2f){t.z, t.z};
    qb2[i][3] = (v2f){t.w, t.w};
    l2[i] = (v2f){0.f, 0.f};
    a01[i] = (v2f){0.f, 0.f};
    a23[i] = (v2f){0.f, 0.f};
  }

#pragma unroll 4
  for (int p = 0; p < 128; ++p) {
    v2f kp0 = KTh[4 * p + 0], kp1 = KTh[4 * p + 1];
    v2f kp2 = KTh[4 * p + 2], kp3 = KTh[4 * p + 3];
    v2f va01 = VTh[4 * p + 0], va23 = VTh[4 * p + 1];
    v2f vb01 = VTh[4 * p + 2], vb23 = VTh[4 * p + 3];
#pragma unroll
    for (int i = 0; i < QB; ++i) {
      v2f s2 = qb2[i][0] * kp0;
      s2 = FMA2(qb2[i][1], kp1, s2);
      s2 = FMA2(qb2[i][2], kp2, s2);
      s2 = FMA2(qb2[i][3], kp3, s2);
      v2f pv;
      pv.x = EXP2(s2.x);
      pv.y = EXP2(s2.y);
      l2[i] += pv;
      v2f pa = pv.xx;
      v2f pb = pv.yy;
      a01[i] = FMA2(pa, va01, a01[i]);
      a23[i] = FMA2(pa, va23, a23[i]);
      a01[i] = FMA2(pb, vb01, a01[i]);
      a23[i] = FMA2(pb, vb23, a23[i]);
    }
  }

#pragma unroll
  for (int i = 0; i < QB; ++i) {
    size_t idx = base + q0 + i * 256;
    LP[idx] = l2[i].x + l2[i].y;
    AP[idx] = make_float4(a01[i].x, a01[i].y, a23[i].x, a23[i].y);
  }
}

// ------- fused: sum split-K partials + analytic key-0 + o-proj + LN1 --------
// 256 thr = 8 rows x 32 lanes. Lane ch = h*4+d.
__global__ __launch_bounds__(256) void k_oproj(const float* __restrict__ LP,
    const float4* __restrict__ AP, const float* __restrict__ qkv,
    float* __restrict__ x, const float* __restrict__ ow,
    const float* __restrict__ ob, const float* __restrict__ g,
    const float* __restrict__ bln) {
  int tid = threadIdx.x;
  int r = tid >> 5, ch = tid & 31;
  int row = blockIdx.x * 8 + r;
  __shared__ float os[8][32];
  bool ok = row < LL;
  if (ok) {
    int h = ch >> 2, d = ch & 3;
    float L = 0.f, A = 0.f;
#pragma unroll
    for (int c = 0; c < NCHUNK; ++c) {
      size_t idx = ((size_t)c * NHEAD + h) * LL + row;
      L += LP[idx];
      A += ((const float*)&AP[idx])[d];
    }
    float4 q4 = *(const float4*)(qkv + (size_t)row * 96 + h * HD);
    float4 k04 = *(const float4*)(qkv + 32 + h * HD);
    float p0 = EXP2(QSCALE * dot4(q4, k04));
    L += p0;
    A = fmaf(p0, qkv[64 + h * HD + d], A);
    os[r][ch] = A / L;
  } else {
    os[r][ch] = 0.f;
  }
  __syncthreads();
  float acc = 0.f;
#pragma unroll
  for (int k = 0; k < 32; ++k) acc = fmaf(os[r][k], ow[ch * 32 + k], acc);
  float val = ok ? (x[(size_t)row * HDIM + ch] + acc + ob[ch]) : 0.f;
  float mean = val;
#pragma unroll
  for (int off = 16; off > 0; off >>= 1) mean += __shfl_xor(mean, off, 32);
  mean *= (1.f / 32.f);
  float d2 = val - mean;
  float var = d2 * d2;
#pragma unroll
  for (int off = 16; off > 0; off >>= 1) var += __shfl_xor(var, off, 32);
  var *= (1.f / 32.f);
  float y = d2 / sqrtf(var + EPSLN) * g[ch] + bln[ch];
  if (ok) x[(size_t)row * HDIM + ch] = y;
}

// ---------------- fused FFN part A: per (row-tile, f-segment) ----------------
__global__ __launch_bounds__(256) void k_ffnA(const float* __restrict__ x,
    const float* __restrict__ w1, const float* __restrict__ b1,
    const float* __restrict__ w2, float* __restrict__ part2) {
  __shared__ float Xs[RT][33];
  __shared__ float W1t[32][132];
  __shared__ float W2t[FS][36];
  __shared__ float Fs[RT][129];
  int tid = threadIdx.x;
  int r0 = blockIdx.x * RT;
  int f0 = blockIdx.y * FS;

#pragma unroll
  for (int p = 0; p < 8; ++p) {
    int idx = p * 256 + tid;
    int r = idx >> 5, k = idx & 31;
    Xs[r][k] = (r0 + r < LL) ? x[(size_t)(r0 + r) * HDIM + k] : 0.f;
  }
#pragma unroll
  for (int p = 0; p < 16; ++p) {
    int idx = p * 256 + tid;
    int c = idx >> 5, k = idx & 31;
    W1t[k][c] = w1[(size_t)(f0 + c) * HDIM + k];
  }
#pragma unroll
  for (int p = 0; p < 16; ++p) {
    int idx = p * 256 + tid;
    int c = idx >> 7, k = idx & 127;
    W2t[k][c] = w2[(size_t)c * FFD + f0 + k];
  }
  __syncthreads();

  int rg = tid >> 4, cg = tid & 15;
  float acc[4][8];
#pragma unroll
  for (int i = 0; i < 4; ++i)
#pragma unroll
    for (int j = 0; j < 8; ++j) acc[i][j] = 0.f;
#pragma unroll
  for (int k = 0; k < 32; ++k) {
    float xv[4];
#pragma unroll
    for (int i = 0; i < 4; ++i) xv[i] = Xs[rg * 4 + i][k];
    float4 w0 = *(const float4*)&W1t[k][cg * 8];
    float4 w1v = *(const float4*)&W1t[k][cg * 8 + 4];
#pragma unroll
    for (int i = 0; i < 4; ++i) {
      acc[i][0] = fmaf(xv[i], w0.x, acc[i][0]);
      acc[i][1] = fmaf(xv[i], w0.y, acc[i][1]);
      acc[i][2] = fmaf(xv[i], w0.z, acc[i][2]);
      acc[i][3] = fmaf(xv[i], w0.w, acc[i][3]);
      acc[i][4] = fmaf(xv[i], w1v.x, acc[i][4]);
      acc[i][5] = fmaf(xv[i], w1v.y, acc[i][5]);
      acc[i][6] = fmaf(xv[i], w1v.z, acc[i][6]);
      acc[i][7] = fmaf(xv[i], w1v.w, acc[i][7]);
    }
  }
#pragma unroll
  for (int j = 0; j < 8; ++j) {
    float bb = b1[f0 + cg * 8 + j];
#pragma unroll
    for (int i = 0; i < 4; ++i)
      Fs[rg * 4 + i][cg * 8 + j] = fmaxf(acc[i][j] + bb, 0.f);
  }
  __syncthreads();

  int kq = tid >> 6, r4 = (tid >> 2) & 15, c8 = tid & 3;
  float a2[4][8];
#pragma unroll
  for (int i = 0; i < 4; ++i)
#pragma unroll
    for (int j = 0; j < 8; ++j) a2[i][j] = 0.f;
  int kbase = kq * 32;
#pragma unroll
  for (int kk = 0; kk < 32; ++kk) {
    int k = kbase + kk;
    float fv[4];
#pragma unroll
    for (int i = 0; i < 4; ++i) fv[i] = Fs[r4 * 4 + i][k];
    float4 u0 = *(const float4*)&W2t[k][c8 * 8];
    float4 u1 = *(const float4*)&W2t[k][c8 * 8 + 4];
#pragma unroll
    for (int i = 0; i < 4; ++i) {
      a2[i][0] = fmaf(fv[i], u0.x, a2[i][0]);
      a2[i][1] = fmaf(fv[i], u0.y, a2[i][1]);
      a2[i][2] = fmaf(fv[i], u0.z, a2[i][2]);
      a2[i][3] = fmaf(fv[i], u0.w, a2[i][3]);
      a2[i][4] = fmaf(fv[i], u1.x, a2[i][4]);
      a2[i][5] = fmaf(fv[i], u1.y, a2[i][5]);
      a2[i][6] = fmaf(fv[i], u1.z, a2[i][6]);
      a2[i][7] = fmaf(fv[i], u1.w, a2[i][7]);
    }
  }
  for (int q = 0; q < 4; ++q) {
    if (kq == q) {
#pragma unroll
      for (int i = 0; i < 4; ++i)
#pragma unroll
        for (int j = 0; j < 8; ++j) {
          int rr = r4 * 4 + i, cc = c8 * 8 + j;
          if (q == 0) Xs[rr][cc] = a2[i][j];
          else Xs[rr][cc] += a2[i][j];
        }
    }
    __syncthreads();
  }
#pragma unroll
  for (int p = 0; p < 8; ++p) {
    int idx = p * 256 + tid;
    int r = idx >> 5, cc = idx & 31;
    if (r0 + r < LL)
      part2[((size_t)blockIdx.y * LL + r0 + r) * HDIM + cc] = Xs[r][cc];
  }
}

// ------ FFN part B: combine + residual + LN2 + next qkv (+KT/VT) + final ----
__global__ __launch_bounds__(256) void k_ffnB_qkv(float* __restrict__ x,
    const float* __restrict__ part2, const float* __restrict__ b2,
    const float* __restrict__ g, const float* __restrict__ bln,
    const float* __restrict__ qw, const float* __restrict__ qb,
    float* __restrict__ qkv, float* __restrict__ KT, float* __restrict__ VT,
    int do_qkv, const float* __restrict__ cw, const float* __restrict__ cb,
    float* __restrict__ out) {
  __shared__ float xs[8][33];
  int tid = threadIdx.x;
  int r = tid >> 5, ch = tid & 31;
  int row = blockIdx.x * 8 + r;
  bool ok = row < LL;
  float s = 0.f;
  if (ok) {
#pragma unroll
    for (int q = 0; q < NFS; ++q)
      s += part2[((size_t)q * LL + row) * HDIM + ch];
  }
  float val = ok ? (x[(size_t)row * HDIM + ch] + s + b2[ch]) : 0.f;
  float mean = val;
#pragma unroll
  for (int off = 16; off > 0; off >>= 1) mean += __shfl_xor(mean, off, 32);
  mean *= (1.f / 32.f);
  float d = val - mean;
  float var = d * d;
#pragma unroll
  for (int off = 16; off > 0; off >>= 1) var += __shfl_xor(var, off, 32);
  var *= (1.f / 32.f);
  float y = d / sqrtf(var + EPSLN) * g[ch] + bln[ch];
  if (ok) x[(size_t)row * HDIM + ch] = y;
  xs[r][ch] = ok ? y : 0.f;
  __syncthreads();
  if (!do_qkv) {
    // last layer: fused classifier head on row 0
    if (blockIdx.x == 0 && r == 0) {
      float t = y * cw[ch];
#pragma unroll
      for (int off = 16; off > 0; off >>= 1) t += __shfl_xor(t, off, 32);
      if (ch == 0) {
        float z = t + cb[0];
        out[0] = 1.f / (1.f + expf(-z));
      }
    }
    return;
  }
  if (!ok) return;
#pragma unroll
  for (int t3 = 0; t3 < 3; ++t3) {
    int cc = t3 * 32 + ch;
    const float4* wr = (const float4*)(qw + (size_t)cc * HDIM);
    float acc = qb[cc];
#pragma unroll
    for (int k = 0; k < 8; ++k) {
      float4 wv = wr[k];
      acc = fmaf(xs[r][4 * k + 0], wv.x, acc);
      acc = fmaf(xs[r][4 * k + 1], wv.y, acc);
      acc = fmaf(xs[r][4 * k + 2], wv.z, acc);
      acc = fmaf(xs[r][4 * k + 3], wv.w, acc);
    }
    qkv[(size_t)row * 96 + cc] = acc;
    store_ktvt(row, ch, t3, acc, KT, VT);
  }
}

extern "C" void kernel_launch(void* const* d_in, const int* in_sizes, int n_in,
                              void* d_out, int out_size, void* d_ws, size_t ws_size,
                              hipStream_t stream) {
  const float* data  = (const float*)d_in[0];
  const float* lin_w = (const float*)d_in[1];
  const float* lin_b = (const float*)d_in[2];
  const float* qkv_w = (const float*)d_in[3];
  const float* qkv_b = (const float*)d_in[4];
  const float* out_w = (const float*)d_in[5];
  const float* out_b = (const float*)d_in[6];
  const float* ln1_g = (const float*)d_in[7];
  const float* ln1_b = (const float*)d_in[8];
  const float* ff1_w = (const float*)d_in[9];
  const float* ff1_b = (const float*)d_in[10];
  const float* ff2_w = (const float*)d_in[11];
  const float* ff2_b = (const float*)d_in[12];
  const float* ln2_g = (const float*)d_in[13];
  const float* ln2_b = (const float*)d_in[14];
  const float* cls_w = (const float*)d_in[15];
  const float* cls_b = (const float*)d_in[16];

  float* ws = (float*)d_ws;
  float*  X   = ws;                                  // LL*32
  float*  QKV = X + (size_t)LL * 32;                 // LL*96
  float*  KT  = QKV + (size_t)LL * 96;               // 8*2048*8
  float*  VT  = KT + (size_t)8 * 2048 * 8;           // 8*4097*4
  float4* AP  = (float4*)(VT + (size_t)8 * 4097 * 4);        // NCHUNK*NHEAD*LL
  float*  LP  = (float*)(AP + (size_t)NCHUNK * NHEAD * LL);  // NCHUNK*NHEAD*LL
  float*  PART2 = (float*)AP;                        // aliased: disjoint lifetimes

  const int NROWB = (LL + 7) / 8;                    // 513

  k_embed_qkv<<<NROWB, 256, 0, stream>>>(data, lin_w, lin_b, X,
                                         qkv_w, qkv_b, QKV, KT, VT);
  for (int l = 0; l < NLAYER; ++l) {
    k_attn<<<dim3(9, NHEAD, NCHUNK), 256, 0, stream>>>(QKV, KT, VT, LP, AP);
    k_oproj<<<NROWB, 256, 0, stream>>>(
        LP, AP, QKV, X, out_w + (size_t)l * 32 * 32, out_b + (size_t)l * 32,
        ln1_g + (size_t)l * 32, ln1_b + (size_t)l * 32);
    k_ffnA<<<dim3((LL + RT - 1) / RT, NFS), 256, 0, stream>>>(
        X, ff1_w + (size_t)l * FFD * 32, ff1_b + (size_t)l * FFD,
        ff2_w + (size_t)l * 32 * FFD, PART2);
    int nl = l + 1;
    int do_qkv = (nl < NLAYER) ? 1 : 0;
    const float* qw = qkv_w + (size_t)(do_qkv ? nl : 0) * 96 * 32;
    const float* qb = qkv_b + (size_t)(do_qkv ? nl : 0) * 96;
    k_ffnB_qkv<<<NROWB, 256, 0, stream>>>(
        X, PART2, ff2_b + (size_t)l * 32,
        ln2_g + (size_t)l * 32, ln2_b + (size_t)l * 32,
        qw, qb, QKV, KT, VT, do_qkv, cls_w, cls_b, (float*)d_out);
  }
}